// Round 13
// baseline (341.006 us; speedup 1.0000x reference)
//
#include <hip/hip_runtime.h>

typedef _Float16 f16x8 __attribute__((ext_vector_type(8)));
typedef _Float16 f16x4 __attribute__((ext_vector_type(4)));
typedef float    f32x4 __attribute__((ext_vector_type(4)));

#define MFMA(a,b,c) __builtin_amdgcn_mfma_f32_16x16x32_f16((a),(b),(c),0,0,0)

// ws layout (bytes): [0)      M~  f16 [128][128]  (scale * Wk^T Wq)
//                    [32768)  Wv' f16 [128][128]  (Wo @ Wv)
//                    [65536)  biases f32: t[128] = scale*Wk^T bq, b'[128] = Wo bv + bo
//                    [131072) Xg f16 [1024 g][256 rows=(d*8+p)][128 c]  (67.1 MB)
// Algebra: softmax over key-axis i is invariant to per-j offsets, so
//   S[i][j] = x_i^T (M x_j + t)  with M = scale*Wk^T Wq, t = scale*Wk^T bq
// (bk-only and constant terms drop). out = Wv' (X A) + b' + x.
//
// Design rules established R0-R12 (hard-won):
//  - Partial 64B out-lines merge ONLY with co-timed 32B halves: lockstep
//    sibling blocks (R5) or lockstep waves of one block. Persistent loops
//    (R3,R6) and two-pass blocks (R8,R9) always produce 3.4x WRITE + RMW.
//  - attn kernel = R5 measured optimum (88-94us, FETCH 34MB, WRITE 143MB
//    ~= ideal). FROZEN structure — 4 restructuring attempts all regressed.
//  - transpose: v2 (LDS) == v3 (h-loop) == v4 (register-only) -> DRAM-
//    pattern-limited; fused with prep + NT x-loads = ~54us (R12).
//  - ~188us of dur_us is harness workspace re-poison (2x 512MiB fills)
//    — not reducible by kernel design.
// R13: NT loads for Xg in attn P1 (read-once; frees L2/L3 for out-line
// merge window). Everything else frozen.

// ---------------- fused prep + transpose ----------------
// grid = 4096 + 64 blocks, 256 thr.
// Blocks 0..4095: transpose v4 (register-only). Block reads 4c x 4w per
//   thread (f32x4, non-temporal), transposes in registers, stores f16x4 (8B)
//   to Xg; each wave covers 32B per Xg line, the other 32B comes from the
//   co-resident sibling wave of the same block (lockstep merge).
// Blocks 4096..4159: prep — fold weights; 2 output rows per block.
__global__ __launch_bounds__(256) void prep_transpose_kernel(
    const float* __restrict__ x, _Float16* __restrict__ Xg,
    const float* __restrict__ Wk, const float* __restrict__ bk,
    const float* __restrict__ Wq, const float* __restrict__ bq,
    const float* __restrict__ Wv, const float* __restrict__ bv,
    const float* __restrict__ Wo, const float* __restrict__ bo,
    _Float16* __restrict__ wh, float* __restrict__ bf) {
  const int bid = blockIdx.x;
  const int tid = threadIdx.x;
  if (bid >= 4096) {
    // ---- prep path: o = (bid-4096)*2 + half ----
    __shared__ float shK[2][128], shO[2][128];
    const int half = tid >> 7;
    const int c = tid & 127;
    const int o = (bid - 4096)*2 + half;
    const float scale = 0.08838834764831844f;  // 1/sqrt(128)
    shK[half][c] = Wk[c*128 + o];      // Wk[m][o]  (column o)
    shO[half][c] = Wo[o*128 + c];      // Wo[o][m]
    __syncthreads();
    float aM = 0.f, aV = 0.f, tK = 0.f, bV = 0.f;
    for (int m = 0; m < 128; ++m) {
      aM += shK[half][m] * Wq[m*128 + c];   // M[o][c]
      aV += shO[half][m] * Wv[m*128 + c];   // Wv'[o][c]
      tK += shK[half][m] * bq[m];
      bV += shO[half][m] * bv[m];
    }
    wh[o*128 + c]         = (_Float16)(aM * scale);
    wh[16384 + o*128 + c] = (_Float16)aV;
    if (c == 0) { bf[o] = tK * scale; bf[128 + o] = bV + bo[o]; }
    return;
  }
  // ---- transpose path ----
  const int h = bid & 63, d = (bid >> 6) & 31, b = bid >> 11;
  const int wq = tid & 15, cr = tid >> 4;    // w-quad 0..15, c-quad 0..15
  const size_t rbase = (size_t)b*16777216u + (size_t)d*4096 + h*64;
  const int gbase = (b*64 + h)*8;            // 8 groups per (b,h)
#pragma unroll
  for (int pass = 0; pass < 2; ++pass) {
    const int base_c = pass*64 + cr*4;
    f32x4 v[4];
#pragma unroll
    for (int r = 0; r < 4; ++r)
      v[r] = __builtin_nontemporal_load(
               (const f32x4*)(x + rbase + (size_t)(base_c + r)*131072 + wq*4));
#pragma unroll
    for (int p = 0; p < 4; ++p) {
      const int w = wq*4 + p;
      f16x4 t;
#pragma unroll
      for (int r = 0; r < 4; ++r) t[r] = (_Float16)v[r][p];
      *(f16x4*)(Xg + (size_t)(gbase + (w >> 3))*32768
                   + (size_t)(d*8 + (w & 7))*128 + base_c) = t;
    }
  }
}

__device__ __forceinline__ f16x4 cvt4(f32x4 v, f32x4 b) {
  f16x4 r;
  r[0] = (_Float16)(v[0] + b[0]); r[1] = (_Float16)(v[1] + b[1]);
  r[2] = (_Float16)(v[2] + b[2]); r[3] = (_Float16)(v[3] + b[3]);
  return r;
}
__device__ __forceinline__ f16x4 cvt4z(f32x4 v) {
  f16x4 r;
  r[0] = (_Float16)v[0]; r[1] = (_Float16)v[1];
  r[2] = (_Float16)v[2]; r[3] = (_Float16)v[3];
  return r;
}

// XOR swizzle for Xt/Yt [256 rows][128 f16 cols], 256B rows, no padding.
// XOR folds row, row>>3 (stride-8-row accesses) and row>>5 (stride-64) so
// all phase patterns land >=8 distinct 16B chunks per 16 lanes.
__device__ __forceinline__ int xsw(int row, int col /*f16 units*/) {
  return ((row << 8) | (col << 1)) ^ (((row ^ (row >> 3) ^ (row >> 5)) & 7) << 4);
}

// ---------------- fused attention (R5 optimum, frozen structure) ----------------
// grid = 1024 blocks x 1024 thr; 8 consecutive w per block -> each wave's quad
// pair stores 32B per 64B out-line; sibling blocks (bid,bid+8) are co-round +
// same-XCD and complete each line (R5: WRITE 143MB ~= ideal).
// LDS 148KB -> 1 block/CU: all CUs lockstep (the write-merge synchronizer).
__global__ __launch_bounds__(1024, 4) void attn_kernel(
    const _Float16* __restrict__ Xg, const _Float16* __restrict__ wh,
    const float* __restrict__ bfp, float* __restrict__ out) {
  __shared__ __align__(16) char lds[151552];
  char* XtB = lds;                      // [256 r=d*8+p][128 c] f16, swizzled (64KB)
  char* YtB = lds + 65536;              // Y^T, later U^T, swizzled (64KB)
  _Float16* At = (_Float16*)(lds + 131072);  // [p*32+j][40 i] f16 (20KB)

  const int tid  = threadIdx.x;
  const int lane = tid & 63;
  const int wv   = tid >> 6;            // 0..15
  const int quad = lane >> 4;
  const int l15  = lane & 15;

  const int bid = blockIdx.x;
  // sibling pairing: g and g^1 (the two halves of each 64B out-line) are
  // bids 8 apart -> same XCD (bid%8 equal), dispatched adjacently.
  const int g = (bid & ~15) | ((bid & 7) << 1) | ((bid >> 3) & 1);
  const int b   = g >> 9;
  const int rem = g & 511;
  const int h   = rem >> 3;
  const int wg  = rem & 7;
  const size_t pbase = (size_t)b * 16777216u + (size_t)(h*64 + wg*8);
  const f32x4 zz = {0.f, 0.f, 0.f, 0.f};

  // ---- prefetch M~ fragments + bias (in flight during P1) ----
  const int mi = wv & 7, ni = wv >> 3;
  f16x8 wm[4];
#pragma unroll
  for (int kk = 0; kk < 4; ++kk)
    wm[kk] = *(const f16x8*)(wh + (mi*16 + l15)*128 + kk*32 + quad*8);
  const f32x4 t4 = *(const f32x4*)(bfp + mi*16 + quad*4);

  // ---- P1: coalesced NT load of this group's 64KB f16 chunk -> Xt (swizzled).
  // Xg is read-once: NT keeps it out of L2/L3, preserving capacity for the
  // out-line write-merge window. ----
  {
    const _Float16* src = Xg + (size_t)g * 32768;
#pragma unroll
    for (int i = 0; i < 4; ++i) {
      const int idx = tid + i*1024;          // 0..4095
      const int row = idx >> 4, ck = (idx & 15) * 8;
      const f16x8 v = __builtin_nontemporal_load(
                        (const f16x8*)(src + row*128 + ck));
      *(f16x8*)(XtB + xsw(row, ck)) = v;
    }
  }
  __syncthreads();

  // ---- P2: Y = M~ X + t  -> Yt (rows = voxel d*8+p, cols = c1) ----
  {
    f32x4 aY[8] = {zz, zz, zz, zz, zz, zz, zz, zz};
#pragma unroll
    for (int kk = 0; kk < 4; ++kk) {
      const int co = kk*32 + quad*8;
#pragma unroll
      for (int nt = 0; nt < 8; ++nt) {
        const f16x8 bfv = *(const f16x8*)(XtB + xsw(ni*128 + nt*16 + l15, co));
        aY[nt] = MFMA(wm[kk], bfv, aY[nt]);
      }
    }
#pragma unroll
    for (int nt = 0; nt < 8; ++nt)
      *(f16x4*)(YtB + xsw(ni*128 + nt*16 + l15, mi*16 + quad*4)) = cvt4(aY[nt], t4);
  }
  __syncthreads();

  // ---- P3: S = X^T Y per pixel; wave = (pixel p, j-half tj); softmax -> At ----
  {
    const int p = wv & 7, tj = wv >> 3;
    f32x4 aS[2] = {zz, zz};
#pragma unroll
    for (int kk = 0; kk < 4; ++kk) {
      const int co = kk*32 + quad*8;
      const f16x8 by = *(const f16x8*)(YtB + xsw((tj*16 + l15)*8 + p, co));
#pragma unroll
      for (int ti = 0; ti < 2; ++ti) {
        const f16x8 ak = *(const f16x8*)(XtB + xsw((ti*16 + l15)*8 + p, co));
        aS[ti] = MFMA(ak, by, aS[ti]);
      }
    }
    // lane holds S[i = ti*16+quad*4+r][j = tj*16+l15]; reduce over i
    float mx = aS[0][0];
#pragma unroll
    for (int r = 1; r < 4; ++r) mx = fmaxf(mx, aS[0][r]);
#pragma unroll
    for (int r = 0; r < 4; ++r) mx = fmaxf(mx, aS[1][r]);
    mx = fmaxf(mx, __shfl_xor(mx, 16));
    mx = fmaxf(mx, __shfl_xor(mx, 32));
    float e[2][4];
    float den = 0.f;
#pragma unroll
    for (int ti = 0; ti < 2; ++ti)
#pragma unroll
      for (int r = 0; r < 4; ++r) { e[ti][r] = __expf(aS[ti][r] - mx); den += e[ti][r]; }
    den += __shfl_xor(den, 16);
    den += __shfl_xor(den, 32);
    const float rr = 1.0f / den;
#pragma unroll
    for (int ti = 0; ti < 2; ++ti) {
      f16x4 av;
#pragma unroll
      for (int r = 0; r < 4; ++r) av[r] = (_Float16)(e[ti][r] * rr);
      *(f16x4*)(At + (p*32 + tj*16 + l15)*40 + ti*16 + quad*4) = av;
    }
  }
  __syncthreads();

  // ---- P5: U = X A per pixel -> Yt (U^T rows = j*8+p); load Wv' frags ----
  f16x8 wp[4];
  {
#pragma unroll
    for (int kk = 0; kk < 4; ++kk)
      wp[kk] = *(const f16x8*)(wh + 16384 + (mi*16 + l15)*128 + kk*32 + quad*8);
    const int p = wv & 7, mg = wv >> 3;
    f16x8 bA[2];
#pragma unroll
    for (int tj = 0; tj < 2; ++tj)
      bA[tj] = *(const f16x8*)(At + (p*32 + tj*16 + l15)*40 + quad*8);
#pragma unroll
    for (int t2 = 0; t2 < 4; ++t2) {
      const int ms = mg*4 + t2;
      f16x8 ax;
#pragma unroll
      for (int jj = 0; jj < 8; ++jj)
        ax[jj] = *(const _Float16*)(XtB + xsw((quad*8 + jj)*8 + p, ms*16 + l15));
#pragma unroll
      for (int tj = 0; tj < 2; ++tj) {
        const f32x4 aU = MFMA(ax, bA[tj], zz);
        *(f16x4*)(YtB + xsw((tj*16 + l15)*8 + p, ms*16 + quad*4)) = cvt4z(aU);
      }
    }
  }
  __syncthreads();

  // ---- P6: out^T = U^T Wv'^T + b' + x : 32B/line stores (quad pairs) ----
  {
    const int oi = wv & 7, mg6 = wv >> 3;
    f32x4 acc[8] = {zz, zz, zz, zz, zz, zz, zz, zz};
#pragma unroll
    for (int kk = 0; kk < 4; ++kk) {
      const int co = kk*32 + quad*8;
#pragma unroll
      for (int mt = 0; mt < 8; ++mt) {
        const f16x8 av = *(const f16x8*)(YtB + xsw((mg6*8 + mt)*16 + l15, co));
        acc[mt] = MFMA(av, wp[kk], acc[mt]);
      }
    }
    const int o = oi*16 + l15;
    const float bb = bfp[128 + o];
    float* outp = out + pbase + (size_t)o*131072;
#pragma unroll
    for (int mt = 0; mt < 8; ++mt) {
      const int vox0 = (mg6*8 + mt)*16 + quad*4;   // voxel = d*8 + p
      const int d = vox0 >> 3;
      f32x4 v;
#pragma unroll
      for (int r = 0; r < 4; ++r)
        v[r] = acc[mt][r] + bb +
               (float)*(const _Float16*)(XtB + xsw(vox0 + r, o));
      *(f32x4*)(outp + (size_t)d*4096 + (vox0 & 7)) = v;
    }
  }
}

extern "C" void kernel_launch(void* const* d_in, const int* in_sizes, int n_in,
                              void* d_out, int out_size, void* d_ws, size_t ws_size,
                              hipStream_t stream) {
  const float* x  = (const float*)d_in[0];
  const float* Wk = (const float*)d_in[1];
  const float* bk = (const float*)d_in[2];
  const float* Wq = (const float*)d_in[3];
  const float* bq = (const float*)d_in[4];
  const float* Wv = (const float*)d_in[5];
  const float* bv = (const float*)d_in[6];
  const float* Wo = (const float*)d_in[7];
  const float* bo = (const float*)d_in[8];
  float* out = (float*)d_out;
  _Float16* wh = (_Float16*)d_ws;
  float* bf = (float*)((char*)d_ws + 65536);
  _Float16* Xg = (_Float16*)((char*)d_ws + 131072);  // needs 67.1 MB of ws

  prep_transpose_kernel<<<dim3(4160), dim3(256), 0, stream>>>(
      x, Xg, Wk, bk, Wq, bq, Wv, bv, Wo, bo, wh, bf);
  attn_kernel<<<dim3(1024), dim3(1024), 0, stream>>>(Xg, wh, bf, out);
}